// Round 9
// baseline (489.800 us; speedup 1.0000x reference)
//
#include <hip/hip_runtime.h>
#include <hip/hip_bf16.h>
#include <math.h>

typedef __attribute__((ext_vector_type(4))) float f32x4;
typedef __attribute__((ext_vector_type(8))) short s16x8;

#define MAXD 192  // fast-path degree cap for fused softmax (LDS alpha buffer)

// ---------------- CSR-by-dst construction ----------------

__global__ void zero2_kernel(int* __restrict__ a, int* __restrict__ b, int n) {
    int i = blockIdx.x * blockDim.x + threadIdx.x;
    if (i < n) { a[i] = 0; b[i] = 0; }
}

__global__ void hist_kernel(const int* __restrict__ dst, int* __restrict__ counts, int E) {
    int e = blockIdx.x * blockDim.x + threadIdx.x;
    if (e < E) atomicAdd(&counts[dst[e]], 1);
}

#define SCAN_T 1024
__global__ __launch_bounds__(SCAN_T) void scan_kernel(const int* __restrict__ counts,
                                                      int* __restrict__ row_ofs, int Nn) {
    __shared__ int part[SCAN_T];
    int tid = threadIdx.x;
    int chunk = Nn / SCAN_T;
    int base = tid * chunk;
    int sum = 0;
    for (int i = 0; i < chunk; ++i) sum += counts[base + i];
    part[tid] = sum;
    __syncthreads();
    for (int off = 1; off < SCAN_T; off <<= 1) {
        int v = part[tid];
        int u = (tid >= off) ? part[tid - off] : 0;
        __syncthreads();
        part[tid] = v + u;
        __syncthreads();
    }
    if (tid == SCAN_T - 1) row_ofs[Nn] = part[tid];
    int acc = part[tid] - sum;  // exclusive prefix
    for (int i = 0; i < chunk; ++i) { row_ofs[base + i] = acc; acc += counts[base + i]; }
}

__global__ void scatter_kernel(const int* __restrict__ dst, const int* __restrict__ row_ofs,
                               int* __restrict__ cursor, int* __restrict__ perm, int E) {
    int e = blockIdx.x * blockDim.x + threadIdx.x;
    if (e < E) {
        int d = dst[e];
        int pos = atomicAdd(&cursor[d], 1);
        perm[row_ofs[d] + pos] = e;
    }
}

// ---------------- w_as/w_ad precompute ----------------
__global__ void wvec_kernel(const float* __restrict__ W, const float* __restrict__ a_s,
                            const float* __restrict__ a_d, float* __restrict__ w_as,
                            float* __restrict__ w_ad, int DIN, int H, int C) {
    int gid = blockIdx.x * blockDim.x + threadIdx.x;
    int wid = gid >> 6;
    int lane = threadIdx.x & 63;
    if (wid >= H * DIN) return;
    int h = wid / DIN, i = wid % DIN;
    const float* wp = W + (size_t)i * H * C + (size_t)h * C;
    const float* sp = a_s + (size_t)h * C;
    const float* dp = a_d + (size_t)h * C;
    float ss = 0.f, sd = 0.f;
    for (int c = lane; c < C; c += 64) {
        float v = wp[c];
        ss += v * sp[c];
        sd += v * dp[c];
    }
    #pragma unroll
    for (int off = 32; off > 0; off >>= 1) {
        ss += __shfl_down(ss, off, 64);
        sd += __shfl_down(sd, off, 64);
    }
    if (lane == 0) { w_as[wid] = ss; w_ad[wid] = sd; }
}

// ---------------- layer-1 alpha dots, w-vectors LDS-cached; one wave per node ----------------
__global__ __launch_bounds__(256) void alpha16_kernel(const float4* __restrict__ x4,
                                                      const float* __restrict__ wv,
                                                      float* __restrict__ as_out,
                                                      float* __restrict__ ad_out) {
    __shared__ float ws[16 * 768];
    int tid = threadIdx.x;
    #pragma unroll
    for (int i = 0; i < 12; ++i)
        ((float4*)ws)[tid + i * 256] = ((const float4*)wv)[tid + i * 256];
    __syncthreads();
    int wvid = tid >> 6, lane = tid & 63;
    int n = blockIdx.x * 4 + wvid;
    float4 xr[3];
    #pragma unroll
    for (int r = 0; r < 3; ++r) xr[r] = x4[(size_t)n * 192 + lane + 64 * r];
    #pragma unroll
    for (int j = 0; j < 16; ++j) {
        const float4* wj = (const float4*)(ws + j * 768);
        float s = 0.f;
        #pragma unroll
        for (int r = 0; r < 3; ++r) {
            float4 wc = wj[lane + 64 * r];
            s += xr[r].x * wc.x + xr[r].y * wc.y + xr[r].z * wc.z + xr[r].w * wc.w;
        }
        #pragma unroll
        for (int off = 32; off > 0; off >>= 1) s += __shfl_down(s, off, 64);
        if (lane == 0) {
            if (j < 8) as_out[n * 8 + j] = s;
            else       ad_out[n * 8 + (j - 8)] = s;
        }
    }
}

// ---------------- FUSED: per-node softmax (8 heads) + 8-head aggregation -> zAB bf16 ----------------
__device__ inline unsigned short bf16_bits(float f) {
    __hip_bfloat16 b = __float2bfloat16(f);
    return *reinterpret_cast<unsigned short*>(&b);
}

__global__ __launch_bounds__(192) void agg8_fused_kernel(
    const float4* __restrict__ x4,    // [N][192]
    const float* __restrict__ as1,    // [N][8]
    const float* __restrict__ ad1,    // [N][8]
    const int* __restrict__ src,
    const int* __restrict__ row_ofs,
    const int* __restrict__ perm,
    float* __restrict__ e1g,          // [E][8] global fallback alpha
    __hip_bfloat16* __restrict__ zAB, // [N][8*768]
    int D4) {
    __shared__ float alds[MAXD * 8];
    __shared__ float mh[8], dh[8];
    int n = blockIdx.x;
    int s = row_ofs[n], t = row_ofs[n + 1];
    int d = t - s;
    int tid = threadIdx.x;
    bool big = d > MAXD;
    if (!big) {
        int eh = tid & 7, ei = tid >> 3;  // ei in 0..23
        float adn = ad1[n * 8 + eh];
        for (int base = 0; base < d; base += 24) {
            int j = base + ei;
            if (j < d) {
                int e = perm[s + j];
                float v = as1[src[e] * 8 + eh] + adn;
                v = v > 0.f ? v : 0.2f * v;
                alds[j * 8 + eh] = v;
            }
        }
        __syncthreads();
        if (tid < 8) {
            float m = -INFINITY;
            for (int j = 0; j < d; ++j) m = fmaxf(m, alds[j * 8 + tid]);
            float den = 0.f;
            for (int j = 0; j < d; ++j) den += __expf(alds[j * 8 + tid] - m);
            mh[tid] = m; dh[tid] = 1.f / (den + 1e-16f);
        }
        __syncthreads();
        for (int base = 0; base < d; base += 24) {
            int j = base + ei;
            if (j < d) alds[j * 8 + eh] = __expf(alds[j * 8 + eh] - mh[eh]) * dh[eh];
        }
        __syncthreads();
    } else {
        if (tid < 8) {
            int hh = tid;
            float adn = ad1[n * 8 + hh];
            float m = -INFINITY;
            for (int j = s; j < t; ++j) {
                float v = as1[src[perm[j]] * 8 + hh] + adn;
                v = v > 0.f ? v : 0.2f * v;
                m = fmaxf(m, v);
            }
            float den = 0.f;
            for (int j = s; j < t; ++j) {
                float v = as1[src[perm[j]] * 8 + hh] + adn;
                v = v > 0.f ? v : 0.2f * v;
                den += __expf(v - m);
            }
            float inv = 1.f / (den + 1e-16f);
            for (int j = s; j < t; ++j) {
                int e = perm[j];
                float v = as1[src[e] * 8 + hh] + adn;
                v = v > 0.f ? v : 0.2f * v;
                e1g[(size_t)e * 8 + hh] = __expf(v - m) * inv;
            }
        }
        __syncthreads();
    }

    // aggregation: thread j handles float4 column j for all 8 heads; 4-edge unroll
    int j = tid;
    float4 acc[8];
    #pragma unroll
    for (int h = 0; h < 8; ++h) acc[h] = make_float4(0.f, 0.f, 0.f, 0.f);
    int k = s;
    for (; k + 3 < t; k += 4) {
        int e0 = perm[k], e1 = perm[k + 1], e2 = perm[k + 2], e3 = perm[k + 3];
        float4 v0 = x4[(size_t)src[e0] * D4 + j];
        float4 v1 = x4[(size_t)src[e1] * D4 + j];
        float4 v2 = x4[(size_t)src[e2] * D4 + j];
        float4 v3 = x4[(size_t)src[e3] * D4 + j];
        const float* a0 = big ? &e1g[(size_t)e0 * 8] : &alds[(k - s) * 8];
        const float* a1 = big ? &e1g[(size_t)e1 * 8] : &alds[(k + 1 - s) * 8];
        const float* a2 = big ? &e1g[(size_t)e2 * 8] : &alds[(k + 2 - s) * 8];
        const float* a3 = big ? &e1g[(size_t)e3 * 8] : &alds[(k + 3 - s) * 8];
        #pragma unroll
        for (int h = 0; h < 8; ++h) {
            float a = a0[h], b = a1[h], c = a2[h], e = a3[h];
            acc[h].x += a * v0.x + b * v1.x + c * v2.x + e * v3.x;
            acc[h].y += a * v0.y + b * v1.y + c * v2.y + e * v3.y;
            acc[h].z += a * v0.z + b * v1.z + c * v2.z + e * v3.z;
            acc[h].w += a * v0.w + b * v1.w + c * v2.w + e * v3.w;
        }
    }
    for (; k < t; ++k) {
        int e0 = perm[k];
        float4 v0 = x4[(size_t)src[e0] * D4 + j];
        const float* a0 = big ? &e1g[(size_t)e0 * 8] : &alds[(k - s) * 8];
        #pragma unroll
        for (int h = 0; h < 8; ++h) {
            float a = a0[h];
            acc[h].x += a * v0.x; acc[h].y += a * v0.y;
            acc[h].z += a * v0.z; acc[h].w += a * v0.w;
        }
    }
    int D = D4 * 4;
    #pragma unroll
    for (int h = 0; h < 8; ++h) {
        size_t o = (size_t)n * 8 * D + (size_t)h * D + j * 4;
        ushort4 st;
        st.x = bf16_bits(acc[h].x); st.y = bf16_bits(acc[h].y);
        st.z = bf16_bits(acc[h].z); st.w = bf16_bits(acc[h].w);
        *reinterpret_cast<ushort4*>(&zAB[o]) = st;
    }
}

// ---------------- FUSED: layer-2 softmax (H=1) + output aggregation (+bias) ----------------
__global__ __launch_bounds__(192) void out_fused_kernel(
    const float4* __restrict__ feat4,  // h2 [N][192]
    const float* __restrict__ as2,     // [N]
    const float* __restrict__ ad2,     // [N]
    const int* __restrict__ src,
    const int* __restrict__ row_ofs,
    const int* __restrict__ perm,
    float* __restrict__ e2g,           // [E] global fallback alpha
    const float4* __restrict__ bias4,
    float4* __restrict__ out4, int D4) {
    __shared__ float alds[MAXD];
    __shared__ float minv[2];
    int n = blockIdx.x;
    int s = row_ofs[n], t = row_ofs[n + 1];
    int d = t - s;
    int tid = threadIdx.x;
    bool big = d > MAXD;
    if (!big) {
        float adn = ad2[n];
        if (tid < d) {
            float v = as2[src[perm[s + tid]]] + adn;
            v = v > 0.f ? v : 0.2f * v;
            alds[tid] = v;
        }
        __syncthreads();
        if (tid == 0) {
            float m = -INFINITY;
            for (int j = 0; j < d; ++j) m = fmaxf(m, alds[j]);
            float den = 0.f;
            for (int j = 0; j < d; ++j) den += __expf(alds[j] - m);
            minv[0] = m; minv[1] = 1.f / (den + 1e-16f);
        }
        __syncthreads();
        if (tid < d) alds[tid] = __expf(alds[tid] - minv[0]) * minv[1];
        __syncthreads();
    } else {
        if (tid == 0) {
            float adn = ad2[n];
            float m = -INFINITY;
            for (int j = s; j < t; ++j) {
                float v = as2[src[perm[j]]] + adn;
                v = v > 0.f ? v : 0.2f * v;
                m = fmaxf(m, v);
            }
            float den = 0.f;
            for (int j = s; j < t; ++j) {
                float v = as2[src[perm[j]]] + adn;
                v = v > 0.f ? v : 0.2f * v;
                den += __expf(v - m);
            }
            float inv = 1.f / (den + 1e-16f);
            for (int j = s; j < t; ++j) {
                int e = perm[j];
                float v = as2[src[e]] + adn;
                v = v > 0.f ? v : 0.2f * v;
                e2g[e] = __expf(v - m) * inv;
            }
        }
        __syncthreads();
    }

    int j = tid;
    float4 acc = make_float4(0.f, 0.f, 0.f, 0.f);
    int k = s;
    for (; k + 3 < t; k += 4) {
        int e0 = perm[k], e1 = perm[k + 1], e2 = perm[k + 2], e3 = perm[k + 3];
        float a = big ? e2g[e0] : alds[k - s];
        float b = big ? e2g[e1] : alds[k + 1 - s];
        float c = big ? e2g[e2] : alds[k + 2 - s];
        float e = big ? e2g[e3] : alds[k + 3 - s];
        float4 v0 = feat4[(size_t)src[e0] * D4 + j];
        float4 v1 = feat4[(size_t)src[e1] * D4 + j];
        float4 v2 = feat4[(size_t)src[e2] * D4 + j];
        float4 v3 = feat4[(size_t)src[e3] * D4 + j];
        acc.x += a * v0.x + b * v1.x + c * v2.x + e * v3.x;
        acc.y += a * v0.y + b * v1.y + c * v2.y + e * v3.y;
        acc.z += a * v0.z + b * v1.z + c * v2.z + e * v3.z;
        acc.w += a * v0.w + b * v1.w + c * v2.w + e * v3.w;
    }
    for (; k < t; ++k) {
        int e0 = perm[k];
        float a = big ? e2g[e0] : alds[k - s];
        float4 v0 = feat4[(size_t)src[e0] * D4 + j];
        acc.x += a * v0.x; acc.y += a * v0.y; acc.z += a * v0.z; acc.w += a * v0.w;
    }
    float4 b = bias4[j];
    acc.x += b.x; acc.y += b.y; acc.z += b.z; acc.w += b.w;
    out4[(size_t)n * D4 + j] = acc;
}

// ---------------- transpose + fp32->bf16 ----------------
__global__ void transpose_bf16_kernel(const float* __restrict__ src, __hip_bfloat16* __restrict__ dst,
                                      int R, int Cc) {
    __shared__ float tile[32][33];
    int bx = blockIdx.x * 32;
    int by = blockIdx.y * 32;
    int tx = threadIdx.x, ty = threadIdx.y;  // 32 x 8
    #pragma unroll
    for (int i = 0; i < 32; i += 8)
        tile[ty + i][tx] = src[(size_t)(by + ty + i) * Cc + (bx + tx)];
    __syncthreads();
    #pragma unroll
    for (int i = 0; i < 32; i += 8)
        dst[(size_t)(bx + ty + i) * R + (by + tx)] = __float2bfloat16(tile[tx][ty + i]);
}

// ---------------- fused: h2 = p0+p1 (split-K S=2); as2/ad2 = h2 . a_s2 / a_d2 ----------------
__global__ __launch_bounds__(192) void reduce_dot_kernel(
    const float4* __restrict__ parts,  // [2][N][192]
    const float4* __restrict__ as_w, const float4* __restrict__ ad_w,
    float4* __restrict__ h2,
    float* __restrict__ as_out, float* __restrict__ ad_out, int NC4) {
    int n = blockIdx.x;
    int j = threadIdx.x;
    size_t idx = (size_t)n * 192 + j;
    float4 a = parts[idx];
    float4 p1 = parts[(size_t)NC4 + idx];
    a.x += p1.x; a.y += p1.y; a.z += p1.z; a.w += p1.w;
    h2[idx] = a;
    float4 ws = as_w[j], wd = ad_w[j];
    float ss = a.x * ws.x + a.y * ws.y + a.z * ws.z + a.w * ws.w;
    float sd = a.x * wd.x + a.y * wd.y + a.z * wd.z + a.w * wd.w;
    #pragma unroll
    for (int off = 32; off > 0; off >>= 1) {
        ss += __shfl_down(ss, off, 64);
        sd += __shfl_down(sd, off, 64);
    }
    __shared__ float red_s[3], red_d[3];
    int wv = j >> 6, lane = j & 63;
    if (lane == 0) { red_s[wv] = ss; red_d[wv] = sd; }
    __syncthreads();
    if (j == 0) {
        as_out[n] = red_s[0] + red_s[1] + red_s[2];
        ad_out[n] = red_d[0] + red_d[1] + red_d[2];
    }
}

// ---------------- bf16 MFMA GEMM: C[M,N] = A[M,K] @ BT[N,K]^T ----------------
// ROUND-7 PROVEN STRUCTURE — do not re-introduce LDS ping-pong (round 8 post-mortem:
// 8 outstanding global_load_lds under one barrier pair corrupted results on graph
// replay; 4-load BK=32 is the m97-validated shape).
// 128x128 tile, BK=32, 256 threads (2x2 waves of 64x64), global_load_lds staging,
// XCD-clustering swizzle (requires (GY*GZ)%8==0), hoisted staging pointers.
__device__ inline void gload_lds16(const void* g, void* l) {
    __builtin_amdgcn_global_load_lds((const __attribute__((address_space(1))) unsigned int*)g,
                                     (__attribute__((address_space(3))) unsigned int*)l, 16, 0, 0);
}

__global__ __launch_bounds__(256) void gemm_bf16_kernel(
    const __hip_bfloat16* __restrict__ A,   // [M][lda]
    const __hip_bfloat16* __restrict__ BT,  // [N][ldb]
    int lda, int ldb, int ldc,
    int K, int kofs_per_z,
    const float* __restrict__ bias,
    __hip_bfloat16* __restrict__ Cb,        // bf16 out or null
    float* __restrict__ Cf,                 // fp32 out (used if Cb==null)
    int flags,                              // 1 = elu
    long bsA, long bsBT, long bsC, long bsBias,
    int GX, int GY) {
    __shared__ short As[128][32];
    __shared__ short Bs[128][32];

    int lin = blockIdx.x;
    int xcd = lin & 7;
    int u = lin >> 3;
    int bx = u % GX;
    int cg = u / GX;
    int cc = cg * 8 + xcd;
    int by = cc % GY;
    int bz = cc / GY;

    int kofs = bz * kofs_per_z;
    A += (size_t)bz * bsA;
    BT += (size_t)bz * bsBT;
    if (Cb) Cb += (size_t)bz * bsC;
    else    Cf += (size_t)bz * bsC;
    if (bias) bias += (size_t)bz * bsBias;

    int tid = threadIdx.x;
    int lane = tid & 63;
    int wv = tid >> 6;
    int wr = (wv >> 1) * 64;
    int wc = (wv & 1) * 64;
    int ml = lane & 15;
    int q8 = (lane >> 4) * 8;

    int col0 = bx * 128;
    int row0 = by * 128;

    // hoisted staging pointers: thread stages rows (tid>>2) and (tid>>2)+64,
    // k-offset (tid&3)*8; advance 32 elements per iteration
    const __hip_bfloat16* gA = A + (size_t)(row0 + (tid >> 2)) * lda + kofs + ((tid & 3) << 3);
    const __hip_bfloat16* gB = BT + (size_t)(col0 + (tid >> 2)) * ldb + kofs + ((tid & 3) << 3);
    size_t strA = (size_t)64 * lda, strB = (size_t)64 * ldb;
    short* lA0 = ((short*)As) + tid * 8;
    short* lA1 = ((short*)As) + (tid + 256) * 8;
    short* lB0 = ((short*)Bs) + tid * 8;
    short* lB1 = ((short*)Bs) + (tid + 256) * 8;

    // hoisted fragment pointers (constant LDS addresses)
    const s16x8* pA[4];
    const s16x8* pB[4];
    #pragma unroll
    for (int t = 0; t < 4; ++t) {
        pA[t] = (const s16x8*)&As[wr + t * 16 + ml][q8];
        pB[t] = (const s16x8*)&Bs[wc + t * 16 + ml][q8];
    }

    f32x4 acc[4][4];
    #pragma unroll
    for (int i = 0; i < 4; ++i)
        #pragma unroll
        for (int j = 0; j < 4; ++j) acc[i][j] = (f32x4){0.f, 0.f, 0.f, 0.f};

    for (int k0 = 0; k0 < K; k0 += 32) {
        gload_lds16(gA, lA0);
        gload_lds16(gA + strA, lA1);
        gload_lds16(gB, lB0);
        gload_lds16(gB + strB, lB1);
        gA += 32; gB += 32;
        __syncthreads();
        s16x8 af[4], bfr[4];
        #pragma unroll
        for (int t = 0; t < 4; ++t) af[t] = *pA[t];
        #pragma unroll
        for (int t = 0; t < 4; ++t) bfr[t] = *pB[t];
        #pragma unroll
        for (int ti = 0; ti < 4; ++ti)
            #pragma unroll
            for (int tj = 0; tj < 4; ++tj)
                acc[ti][tj] = __builtin_amdgcn_mfma_f32_16x16x32_bf16(af[ti], bfr[tj], acc[ti][tj], 0, 0, 0);
        __syncthreads();
    }

    int rbase = row0 + wr + (lane >> 4) * 4;
    int cbase = col0 + wc + ml;
    #pragma unroll
    for (int ti = 0; ti < 4; ++ti) {
        #pragma unroll
        for (int tj = 0; tj < 4; ++tj) {
            int col = cbase + tj * 16;
            float bv = bias ? bias[col] : 0.f;
            #pragma unroll
            for (int r = 0; r < 4; ++r) {
                int row = rbase + ti * 16 + r;
                float v = acc[ti][tj][r] + bv;
                if (flags & 1) {
                    float ev = __expf(v) - 1.f;  // elu via fast exp (select, no branch)
                    v = v > 0.f ? v : ev;
                }
                size_t idx = (size_t)row * ldc + col;
                if (Cb) Cb[idx] = __float2bfloat16(v);
                else    Cf[idx] = v;
            }
        }
    }
}

// ---------------- launch ----------------
extern "C" void kernel_launch(void* const* d_in, const int* in_sizes, int n_in,
                              void* d_out, int out_size, void* d_ws, size_t ws_size,
                              hipStream_t stream) {
    const int N = 8192, E = 65536, DIN = 768, C = 768, H1n = 8;
    const int HC1 = H1n * C;  // 6144

    const float* x    = (const float*)d_in[0];
    const float* W1   = (const float*)d_in[1];
    const float* a_s1 = (const float*)d_in[2];
    const float* a_d1 = (const float*)d_in[3];
    const float* b1   = (const float*)d_in[4];
    const float* W2   = (const float*)d_in[5];
    const float* a_s2 = (const float*)d_in[6];
    const float* a_d2 = (const float*)d_in[7];
    const float* b2   = (const float*)d_in[8];
    const int*   edges = (const int*)d_in[9];
    const int* src = edges;
    const int* dst = edges + E;

    // ---- workspace layout (~248.7 MB) ----
    char* w = (char*)d_ws;
    auto alloc = [&](size_t bytes) -> void* {
        void* p = (void*)w;
        w += (bytes + 255) & ~(size_t)255;
        return p;
    };
    __hip_bfloat16* zAB = (__hip_bfloat16*)alloc((size_t)N * HC1 * 2);      // 100.7 MB
    __hip_bfloat16* o1  = (__hip_bfloat16*)alloc((size_t)N * HC1 * 2);      // 100.7 MB
    float* h2           = (float*)alloc((size_t)N * C * 4);                 // 25.2 MB
    __hip_bfloat16* W1T = (__hip_bfloat16*)alloc((size_t)HC1 * DIN * 2);    // 9.4 MB
    __hip_bfloat16* W2T = (__hip_bfloat16*)alloc((size_t)C * HC1 * 2);      // 9.4 MB
    float* wv      = (float*)alloc((size_t)16 * DIN * 4);
    float* as1     = (float*)alloc((size_t)N * H1n * 4);
    float* ad1     = (float*)alloc((size_t)N * H1n * 4);
    float* e1      = (float*)alloc((size_t)E * H1n * 4);   // fallback alpha (deg > MAXD)
    float* as2     = (float*)alloc((size_t)N * 4);
    float* ad2     = (float*)alloc((size_t)N * 4);
    float* e2      = (float*)alloc((size_t)E * 4);         // fallback alpha (deg > MAXD)
    int*   counts  = (int*)alloc((size_t)N * 4);
    int*   cursor  = (int*)alloc((size_t)N * 4);
    int*   row_ofs = (int*)alloc((size_t)(N + 1) * 4);
    int*   perm    = (int*)alloc((size_t)E * 4);

    // split-K partials for GEMM2 (S=2) alias zAB (dead after GEMM1; 2*25.2 <= 100.7 MB)
    float* partials = (float*)zAB;
    const int S = 2;

    // ---- CSR by dst ----
    zero2_kernel<<<(N + 255) / 256, 256, 0, stream>>>(counts, cursor, N);
    hist_kernel<<<(E + 255) / 256, 256, 0, stream>>>(dst, counts, E);
    scan_kernel<<<1, SCAN_T, 0, stream>>>(counts, row_ofs, N);
    scatter_kernel<<<(E + 255) / 256, 256, 0, stream>>>(dst, row_ofs, cursor, perm, E);

    // ---- weight transforms (bf16, transposed) ----
    {
        dim3 b(32, 8);
        dim3 g1(HC1 / 32, DIN / 32);
        transpose_bf16_kernel<<<g1, b, 0, stream>>>(W1, W1T, DIN, HC1);
        dim3 g2(C / 32, HC1 / 32);
        transpose_bf16_kernel<<<g2, b, 0, stream>>>(W2, W2T, HC1, C);
    }

    // ---- Layer 1 attention coefficients ----
    wvec_kernel<<<(H1n * DIN * 64 + 255) / 256, 256, 0, stream>>>(W1, a_s1, a_d1, wv, wv + 8 * DIN, DIN, H1n, C);
    alpha16_kernel<<<N / 4, 256, 0, stream>>>((const float4*)x, wv, as1, ad1);

    // ---- fused softmax + 8-head aggregation: x -> zAB (bf16) ----
    agg8_fused_kernel<<<N, 192, 0, stream>>>((const float4*)x, as1, ad1, src, row_ofs, perm,
                                             e1, zAB, DIN / 4);

    // ---- GEMM1: all 8 heads; o1 = ELU(z @ W1 + b1) ----
    {
        int GX = C / 128, GY = N / 128, GZ = H1n;  // 6 x 64 x 8 = 3072 blocks
        gemm_bf16_kernel<<<GX * GY * GZ, 256, 0, stream>>>(
            zAB, W1T,
            HC1, DIN, HC1,
            DIN, /*kofs_per_z=*/0,
            b1, o1, nullptr, /*flags=*/1,
            /*bsA=*/C, /*bsBT=*/(long)C * DIN, /*bsC=*/C, /*bsBias=*/C,
            GX, GY);
    }
    // ---- GEMM2: K=6144 split-K S=2 into partials (aliasing zAB) ----
    {
        int GX = C / 128, GY = N / 128, GZ = S;  // 6 x 64 x 2 = 768 blocks
        int Kslice = HC1 / S;                    // 3072 -> 96 iters/block
        gemm_bf16_kernel<<<GX * GY * GZ, 256, 0, stream>>>(
            o1, W2T,
            HC1, HC1, C,
            Kslice, /*kofs_per_z=*/Kslice,
            nullptr, nullptr, partials, /*flags=*/0,
            0, 0, /*bsC=*/(long)N * C, 0,
            GX, GY);
    }

    // ---- fused: h2 = p0 + p1 ; as2/ad2 = h2 . a_s2 / a_d2 ----
    reduce_dot_kernel<<<N, 192, 0, stream>>>((const float4*)partials, (const float4*)a_s2,
                                             (const float4*)a_d2, (float4*)h2, as2, ad2, N * C / 4);

    // ---- fused layer-2 softmax + output aggregation ----
    out_fused_kernel<<<N, 192, 0, stream>>>((const float4*)h2, as2, ad2, src, row_ofs, perm,
                                            e2, (const float4*)b2, (float4*)d_out, C / 4);
}